// Round 7
// baseline (345.369 us; speedup 1.0000x reference)
//
#include <hip/hip_runtime.h>
#include <hip/hip_bf16.h>
#include <math.h>

#define NEG_SLOPE 0.2f

typedef __attribute__((ext_vector_type(8))) short short8;
typedef __attribute__((ext_vector_type(4))) float floatx4;
typedef __attribute__((ext_vector_type(2))) float floatx2;

__device__ inline ushort f2b(float f) {
    __hip_bfloat16 b = __float2bfloat16(f);
    return *(ushort*)&b;
}
// dword holding 2 bf16 (lo, hi) -> floatx2
__device__ inline floatx2 bf2x2(unsigned int d) {
    union { unsigned int i; float f; } lo, hi;
    lo.i = d << 16;
    hi.i = d & 0xffff0000u;
    floatx2 r = {lo.f, hi.f};
    return r;
}

// async global->LDS, 16 B per lane. LDS dest = wave-uniform base + lane*16.
#define GLOAD_LDS16(gp, lp)                                                    \
    __builtin_amdgcn_global_load_lds(                                          \
        (const __attribute__((address_space(1))) unsigned int*)(gp),           \
        (__attribute__((address_space(3))) unsigned int*)(lp), 16, 0, 0)

// ---------------------------------------------------------------------------
// bf16 MFMA GEMM, m97 recipe: C[M,N] = A[M,K] @ Bt[N,K]^T, all bf16 row-major.
// global_load_lds dwordx4 staging into UNPADDED [row][32] LDS (wave-uniform
// base + lane*16 constraint forbids padding). 256 threads = 4 waves.
// BN=128: waves 2x2 of 64x64 (acc[4][4]). BN=64: waves 4x1 of 32x64.
// ---------------------------------------------------------------------------
template<int BM, int BN>
__global__ __launch_bounds__(256) void gemm_bf16(const ushort* __restrict__ A,
                                                 const ushort* __restrict__ Bt,
                                                 ushort* __restrict__ C,
                                                 int M, int N, int K)
{
    constexpr int WTM = (BN == 64) ? 32 : 64;    // wave tile M
    constexpr int WM  = BM / WTM;                // waves along M
    constexpr int IT  = WTM / 16;
    constexpr int JT  = 4;                       // wave tile N = 64
    __shared__ ushort As[BM * 32];
    __shared__ ushort Bs[BN * 32];
    const int tid = threadIdx.x;
    const int w = tid >> 6, lane = tid & 63;
    const int mw = (w % WM) * WTM;
    const int nw = (w / WM) * 64;
    const int m0 = blockIdx.y * BM;
    const int n0 = blockIdx.x * BN;
    const int lm = lane & 15;
    const int kg = lane >> 4;

    // staging coords: idx = it*256 + tid; row = idx>>2, kc = idx&3
    const int srow = tid >> 2, skc = tid & 3;

    floatx4 acc[IT][JT];
#pragma unroll
    for (int i = 0; i < IT; ++i)
#pragma unroll
        for (int j = 0; j < JT; ++j) acc[i][j] = (floatx4)0.f;

    for (int k0 = 0; k0 < K; k0 += 32) {
#pragma unroll
        for (int it = 0; it < BM / 64; ++it) {
            int row = it * 64 + srow;
            int grow = m0 + row;
            if (grow >= M) grow = M - 1;
            GLOAD_LDS16(&A[(size_t)grow * K + k0 + skc * 8],
                        As + (it * 256 + w * 64) * 8);
        }
#pragma unroll
        for (int it = 0; it < BN / 64; ++it) {
            int row = it * 64 + srow;
            GLOAD_LDS16(&Bt[(size_t)(n0 + row) * K + k0 + skc * 8],
                        Bs + (it * 256 + w * 64) * 8);
        }
        __syncthreads();                         // drains vmcnt before barrier
        short8 a[IT], b[JT];
#pragma unroll
        for (int i = 0; i < IT; ++i)
            a[i] = *(const short8*)&As[(mw + i * 16 + lm) * 32 + kg * 8];
#pragma unroll
        for (int j = 0; j < JT; ++j)
            b[j] = *(const short8*)&Bs[(nw + j * 16 + lm) * 32 + kg * 8];
#pragma unroll
        for (int i = 0; i < IT; ++i)
#pragma unroll
            for (int j = 0; j < JT; ++j)
                acc[i][j] = __builtin_amdgcn_mfma_f32_16x16x32_bf16(a[i], b[j], acc[i][j], 0, 0, 0);
        __syncthreads();
    }

#pragma unroll
    for (int i = 0; i < IT; ++i) {
        int rbase = m0 + mw + i * 16 + (lane >> 4) * 4;
#pragma unroll
        for (int j = 0; j < JT; ++j) {
            int col = n0 + nw + j * 16 + lm;
#pragma unroll
            for (int r = 0; r < 4; ++r) {
                int row = rbase + r;
                if (row < M) C[(size_t)row * N + col] = f2b(acc[i][j][r]);
            }
        }
    }
}

// ---------------------------------------------------------------------------
// Fused prep: x fp32->bf16 cast, 4 weight transposes+casts, degree count.
// counts must be zeroed first (stream-ordered memset).
// ---------------------------------------------------------------------------
__global__ void k_prep(const float* __restrict__ x, ushort* __restrict__ xb, int XB,
                       const float* __restrict__ Wl1, const float* __restrict__ Wr1,
                       const float* __restrict__ Wl2, const float* __restrict__ Wr2,
                       ushort* __restrict__ wlr1t, ushort* __restrict__ wlr2t,
                       const int* __restrict__ dst, int E, int* __restrict__ counts)
{
    const int b = blockIdx.x;
    const int t = threadIdx.x;
    if (b < XB) {                                 // x cast: 8 floats/thread
        int i = b * 2048 + t * 8;
        float4 f0 = *(const float4*)&x[i];
        float4 f1 = *(const float4*)&x[i + 4];
        short8 o;
        o[0] = (short)f2b(f0.x); o[1] = (short)f2b(f0.y);
        o[2] = (short)f2b(f0.z); o[3] = (short)f2b(f0.w);
        o[4] = (short)f2b(f1.x); o[5] = (short)f2b(f1.y);
        o[6] = (short)f2b(f1.z); o[7] = (short)f2b(f1.w);
        *(short8*)&xb[i] = o;
    } else if (b < XB + 640) {                    // 163840 weight elements
        int i = (b - XB) * 256 + t;
        if (i < 65536) {
            int k = i >> 8, n = i & 255;
            wlr1t[n * 256 + k] = f2b(Wl1[i]);
        } else if (i < 131072) {
            int j = i - 65536;
            int k = j >> 8, n = j & 255;
            wlr1t[65536 + n * 256 + k] = f2b(Wr1[j]);
        } else if (i < 147456) {
            int j = i - 131072;
            int k = j >> 6, n = j & 63;
            wlr2t[n * 256 + k] = f2b(Wl2[j]);
        } else {
            int j = i - 147456;
            int k = j >> 6, n = j & 63;
            wlr2t[16384 + n * 256 + k] = f2b(Wr2[j]);
        }
    } else {
        int i = (b - XB - 640) * 256 + t;
        if (i < E) atomicAdd(&counts[dst[i]], 1);
    }
}

// ---------------------------------------------------------------------------
// CSR build. csr_off stores BYTE offsets into xlr1 (src*1024); agg2 uses >>2.
// csr_off[E..E+16) zero-padded (by k_fill) so agg prefetches are branchless.
// ---------------------------------------------------------------------------
__global__ void k_chunksum(const int* __restrict__ counts, int N, int* __restrict__ chunk)
{
    __shared__ int sm[256];
    const int t = threadIdx.x;
    const int base = blockIdx.x * 1024;
    int s = 0;
    for (int i = t; i < 1024; i += 256) {
        int idx = base + i;
        s += (idx < N) ? counts[idx] : 0;
    }
    sm[t] = s;
    __syncthreads();
    for (int off = 128; off; off >>= 1) {
        if (t < off) sm[t] += sm[t + off];
        __syncthreads();
    }
    if (t == 0) chunk[blockIdx.x] = sm[0];
}

__global__ void k_scanchunk(int* __restrict__ chunk, int nchunks)
{
    const int t = threadIdx.x;
    int v = (t < nchunks) ? chunk[t] : 0;
    int inc = v;
#pragma unroll
    for (int off = 1; off < 64; off <<= 1) {
        int y = __shfl_up(inc, off);
        if (t >= off) inc += y;
    }
    if (t < nchunks) chunk[t] = inc - v;
    if (t == nchunks - 1) chunk[nchunks] = inc;
}

__global__ void k_scanwrite(const int* __restrict__ counts, int N,
                            const int* __restrict__ chunk,
                            int* __restrict__ offsets, int* __restrict__ cursor)
{
    __shared__ int sm[256];
    const int t = threadIdx.x;
    const int base = blockIdx.x * 1024 + t * 4;
    int v[4];
    int s = 0;
#pragma unroll
    for (int i = 0; i < 4; ++i) {
        v[i] = (base + i < N) ? counts[base + i] : 0;
        s += v[i];
    }
    sm[t] = s;
    __syncthreads();
    for (int off = 1; off < 256; off <<= 1) {
        int y = (t >= off) ? sm[t - off] : 0;
        __syncthreads();
        sm[t] += y;
        __syncthreads();
    }
    int run = chunk[blockIdx.x] + sm[t] - s;
#pragma unroll
    for (int i = 0; i < 4; ++i) {
        if (base + i < N) {
            offsets[base + i] = run;
            cursor[base + i] = run;
        }
        run += v[i];
    }
    if (blockIdx.x == 0 && t == 0) offsets[N] = chunk[gridDim.x];
}

__global__ void k_fill(const int* __restrict__ src, const int* __restrict__ dst,
                       int E, int* __restrict__ cursor, int* __restrict__ csr_off)
{
    int i = blockIdx.x * blockDim.x + threadIdx.x;
    if (i < E) {
        int d = dst[i];
        int pos = atomicAdd(&cursor[d], 1);
        csr_off[pos] = src[i] * 1024;             // byte offset into xlr1 rows
    }
    if (i < 16) csr_off[E + i] = 0;               // pad: branchless prefetch
}

// ---------------------------------------------------------------------------
// Layer-1 aggregation: one wave per node, 2 edge-slots x 32 lanes, 8 ch/lane.
// Branchless depth-2 gather prefetch (padded csr_off makes all lookaheads
// memory-safe), packed fp32, single-exp online softmax, slot merge at end.
// xlr: row 1024 B (xl at +0, xr at +512 B).
// ---------------------------------------------------------------------------
__global__ __launch_bounds__(256) void agg1(const ushort* __restrict__ xlr,
                                            const float* __restrict__ att,
                                            const float* __restrict__ bias,
                                            const int* __restrict__ offsets,
                                            const int* __restrict__ csr_off,
                                            ushort* __restrict__ h1, int N)
{
    const int wave = blockIdx.x * 4 + (threadIdx.x >> 6);
    const int lane = threadIdx.x & 63;
    if (wave >= N) return;
    const int n = wave;
    const int g = lane >> 5;                        // edge slot 0/1
    const int sl = lane & 31;
    const int elem = (sl >> 2) * 32 + (sl & 3) * 8; // head*32 + quad*8
    const char* __restrict__ xbase = (const char*)xlr;
    const int ebyte = elem * 2;

    floatx2 attv2[4], xrv2[4];
    {
        uint4 xr8 = *(const uint4*)(xbase + (size_t)n * 1024 + 512 + ebyte);
        unsigned int xw[4] = {xr8.x, xr8.y, xr8.z, xr8.w};
#pragma unroll
        for (int i = 0; i < 4; ++i) {
            attv2[i] = *(const floatx2*)&att[elem + 2 * i];
            xrv2[i] = bf2x2(xw[i]);
        }
    }
    float m = -1e30f, l = 0.f;
    floatx2 acc2[4] = {(floatx2)0.f, (floatx2)0.f, (floatx2)0.f, (floatx2)0.f};

    const int beg = offsets[n], end = offsets[n + 1];
    uint4 vA, vB;
    int oC;
    {
        int k0 = beg + g;
        vA = *(const uint4*)(xbase + (unsigned)csr_off[k0] + ebyte);
        vB = *(const uint4*)(xbase + (unsigned)csr_off[k0 + 2] + ebyte);
        oC = csr_off[k0 + 4];
    }
    for (int kk = beg + g; kk < end; kk += 2) {
        uint4 cur = vA;
        vA = vB;
        vB = *(const uint4*)(xbase + (unsigned)oC + ebyte);
        oC = csr_off[kk + 6];

        unsigned int cw[4] = {cur.x, cur.y, cur.z, cur.w};
        floatx2 xl2[4];
        floatx2 u2 = (floatx2)0.f;
#pragma unroll
        for (int i = 0; i < 4; ++i) {
            xl2[i] = bf2x2(cw[i]);
            floatx2 t = xl2[i] + xrv2[i];
            t = __builtin_elementwise_max(t, t * NEG_SLOPE);   // leaky relu
            u2 += t * attv2[i];
        }
        float u = u2.x + u2.y;
        u += __shfl_xor(u, 1);                      // 4-lane channel-group reduce
        u += __shfl_xor(u, 2);
        // single-exp branchless online softmax update
        float e = __expf(-fabsf(u - m));
        bool kp = (m >= u);
        float sc = kp ? 1.f : e;
        float p  = kp ? e : 1.f;
        m = fmaxf(m, u);
#pragma unroll
        for (int i = 0; i < 4; ++i) acc2[i] = acc2[i] * sc + xl2[i] * p;
        l = fmaf(l, sc, p);
    }
    // merge the two slot states (butterfly over lane^32)
    {
        float mo = __shfl_xor(m, 32);
        float lo = __shfl_xor(l, 32);
        float nm = fmaxf(m, mo);
        float ea = __expf(m - nm);
        float eb = __expf(mo - nm);
#pragma unroll
        for (int i = 0; i < 4; ++i) {
            floatx2 ao = {__shfl_xor(acc2[i].x, 32), __shfl_xor(acc2[i].y, 32)};
            acc2[i] = acc2[i] * ea + ao * eb;
        }
        l = l * ea + lo * eb;
    }
    if (g == 0) {
        float rl = 1.f / (l + 1e-16f);
        short8 o;
#pragma unroll
        for (int i = 0; i < 4; ++i) {
            float v0 = fmaf(acc2[i].x, rl, bias[elem + 2 * i]);
            float v1 = fmaf(acc2[i].y, rl, bias[elem + 2 * i + 1]);
            o[2 * i]     = (short)f2b(fmaxf(v0, 0.f));
            o[2 * i + 1] = (short)f2b(fmaxf(v1, 0.f));
        }
        *(short8*)&h1[(size_t)n * 256 + elem] = o;
    }
}

// ---------------------------------------------------------------------------
// Layer-2 aggregation: one wave per node, 8 edge-slots x 8 lanes, 8 ch/lane
// (uint4 = 16 B gather/lane). 3-shuffle logit reduce, branchless depth-1
// prefetch, 3-stage slot merge, fused bias + log_softmax epilogue.
// xlr2: row 256 B (xl at +0, xr at +128 B); row byte offset = csr_off>>2.
// ---------------------------------------------------------------------------
__global__ __launch_bounds__(256) void agg2(const ushort* __restrict__ xlr,
                                            const float* __restrict__ att,
                                            const float* __restrict__ bias,
                                            const int* __restrict__ offsets,
                                            const int* __restrict__ csr_off,
                                            float* __restrict__ out, int N)
{
    const int wave = blockIdx.x * 4 + (threadIdx.x >> 6);
    const int lane = threadIdx.x & 63;
    if (wave >= N) return;
    const int n = wave;
    const int g = lane >> 3;          // slot 0..7
    const int cl = lane & 7;          // channel octet
    const char* __restrict__ xbase = (const char*)xlr;
    const int cbyte = cl * 16;        // 8 bf16

    floatx2 attv2[4], xrv2[4];
    {
        uint4 xr8 = *(const uint4*)(xbase + (size_t)n * 256 + 128 + cbyte);
        unsigned int xw[4] = {xr8.x, xr8.y, xr8.z, xr8.w};
#pragma unroll
        for (int i = 0; i < 4; ++i) {
            attv2[i] = *(const floatx2*)&att[cl * 8 + 2 * i];
            xrv2[i] = bf2x2(xw[i]);
        }
    }
    float m = -1e30f, l = 0.f;
    floatx2 acc2[4] = {(floatx2)0.f, (floatx2)0.f, (floatx2)0.f, (floatx2)0.f};

    const int beg = offsets[n], end = offsets[n + 1];
    uint4 vA;
    int oB;
    {
        int k0 = beg + g;
        vA = *(const uint4*)(xbase + ((unsigned)csr_off[k0] >> 2) + cbyte);
        oB = csr_off[k0 + 8];
    }
    for (int kk = beg + g; kk < end; kk += 8) {
        uint4 cur = vA;
        vA = *(const uint4*)(xbase + ((unsigned)oB >> 2) + cbyte);
        oB = csr_off[kk + 16];

        unsigned int cw[4] = {cur.x, cur.y, cur.z, cur.w};
        floatx2 xl2[4];
        floatx2 u2 = (floatx2)0.f;
#pragma unroll
        for (int i = 0; i < 4; ++i) {
            xl2[i] = bf2x2(cw[i]);
            floatx2 t = xl2[i] + xrv2[i];
            t = __builtin_elementwise_max(t, t * NEG_SLOPE);
            u2 += t * attv2[i];
        }
        float u = u2.x + u2.y;
        u += __shfl_xor(u, 1);                     // 8-lane channel reduce
        u += __shfl_xor(u, 2);
        u += __shfl_xor(u, 4);
        float e = __expf(-fabsf(u - m));
        bool kp = (m >= u);
        float sc = kp ? 1.f : e;
        float p  = kp ? e : 1.f;
        m = fmaxf(m, u);
#pragma unroll
        for (int i = 0; i < 4; ++i) acc2[i] = acc2[i] * sc + xl2[i] * p;
        l = fmaf(l, sc, p);
    }
    // merge the 8 slot states (butterfly over lane^{8,16,32})
#pragma unroll
    for (int off = 8; off <= 32; off <<= 1) {
        float mo = __shfl_xor(m, off);
        float lo = __shfl_xor(l, off);
        float nm = fmaxf(m, mo);
        float sa = __expf(m - nm);
        float sb = __expf(mo - nm);
#pragma unroll
        for (int i = 0; i < 4; ++i) {
            floatx2 ao = {__shfl_xor(acc2[i].x, off), __shfl_xor(acc2[i].y, off)};
            acc2[i] = acc2[i] * sa + ao * sb;
        }
        l = l * sa + lo * sb;
        m = nm;
    }
    float rl = 1.f / (l + 1e-16f);
    float h[8];
#pragma unroll
    for (int i = 0; i < 4; ++i) {
        h[2 * i]     = fmaf(acc2[i].x, rl, bias[cl * 8 + 2 * i]);
        h[2 * i + 1] = fmaf(acc2[i].y, rl, bias[cl * 8 + 2 * i + 1]);
    }

    // log_softmax over 64 channels (8/lane x 8 lanes)
    float mx = h[0];
#pragma unroll
    for (int i = 1; i < 8; ++i) mx = fmaxf(mx, h[i]);
    mx = fmaxf(mx, __shfl_xor(mx, 1));
    mx = fmaxf(mx, __shfl_xor(mx, 2));
    mx = fmaxf(mx, __shfl_xor(mx, 4));
    float ssum = 0.f;
#pragma unroll
    for (int i = 0; i < 8; ++i) ssum += __expf(h[i] - mx);
    ssum += __shfl_xor(ssum, 1);
    ssum += __shfl_xor(ssum, 2);
    ssum += __shfl_xor(ssum, 4);
    float lg = mx + __logf(ssum);
    if (g == 0) {
        float4 o0 = make_float4(h[0], h[1], h[2], h[3]);
        float4 o1 = make_float4(h[4], h[5], h[6], h[7]);
        *(float4*)&out[(size_t)n * 64 + cl * 8] = o0;
        *(float4*)&out[(size_t)n * 64 + cl * 8 + 4] = o1;
        float4 s0 = make_float4(h[0] - lg, h[1] - lg, h[2] - lg, h[3] - lg);
        float4 s1 = make_float4(h[4] - lg, h[5] - lg, h[6] - lg, h[7] - lg);
        *(float4*)&out[(size_t)(N + n) * 64 + cl * 8] = s0;
        *(float4*)&out[(size_t)(N + n) * 64 + cl * 8 + 4] = s1;
    }
}

// ---------------------------------------------------------------------------
extern "C" void kernel_launch(void* const* d_in, const int* in_sizes, int n_in,
                              void* d_out, int out_size, void* d_ws, size_t ws_size,
                              hipStream_t stream)
{
    const float* x    = (const float*)d_in[0];
    const int*   ei   = (const int*)d_in[1];
    const float* Wl1  = (const float*)d_in[2];
    const float* Wr1  = (const float*)d_in[3];
    const float* att1 = (const float*)d_in[4];
    const float* b1   = (const float*)d_in[5];
    const float* Wl2  = (const float*)d_in[6];
    const float* Wr2  = (const float*)d_in[7];
    const float* att2 = (const float*)d_in[8];
    const float* b2   = (const float*)d_in[9];
    float* out = (float*)d_out;

    const int F = 256;
    const int E = in_sizes[1] / 2;
    const int N = in_sizes[0] / F;

    const int* e_src = ei;
    const int* e_dst = ei + E;

    // ---- workspace layout ----
    ushort* xb    = (ushort*)d_ws;                   // [N][256] bf16 x
    ushort* wlr1t = xb + (size_t)N * 256;            // [512][256]  (Wl1|Wr1)^T
    ushort* wlr2t = wlr1t + 512 * 256;               // [128][256]  (Wl2|Wr2)^T
    ushort* xlr1  = wlr2t + 128 * 256;               // [N][512]  xl|xr
    ushort* h1b   = xlr1 + (size_t)N * 512;          // [N][256]
    ushort* xlr2  = h1b + (size_t)N * 256;           // [N][128]  xl|xr
    int* offsets  = (int*)(xlr2 + (size_t)N * 128);  // N+1
    int* cursor   = offsets + (N + 1);               // N+1
    int* counts   = cursor + (N + 1);                // N
    int* chunkoff = counts + N;                      // <=64+1
    int* csr_off  = chunkoff + 66;                   // E+16 (byte offsets, padded)

    const int nchunks = (N + 1023) / 1024;
    const int XB = (N * 256) / 2048;                 // x-cast blocks (8 elem/thread)

    // ---- fused prep (x cast + weights cast/transpose + degree count) ----
    hipMemsetAsync(counts, 0, (size_t)N * sizeof(int), stream);
    k_prep<<<XB + 640 + (E + 255) / 256, 256, 0, stream>>>(
        x, xb, XB, Wl1, Wr1, Wl2, Wr2, wlr1t, wlr2t, e_dst, E, counts);

    // ---- layer-1 GEMM (independent of CSR scan chain) ----
    gemm_bf16<128, 128><<<dim3(4, (N + 127) / 128), 256, 0, stream>>>(xb, wlr1t, xlr1, N, 512, F);

    // ---- CSR scan + fill ----
    k_chunksum<<<nchunks, 256, 0, stream>>>(counts, N, chunkoff);
    k_scanchunk<<<1, 64, 0, stream>>>(chunkoff, nchunks);
    k_scanwrite<<<nchunks, 256, 0, stream>>>(counts, N, chunkoff, offsets, cursor);
    k_fill<<<(E + 255) / 256, 256, 0, stream>>>(e_src, e_dst, E, cursor, csr_off);

    // ---- layer 1 aggregate ----
    agg1<<<(N + 3) / 4, 256, 0, stream>>>(xlr1, att1, b1, offsets, csr_off, h1b, N);

    // ---- layer 2 ----
    gemm_bf16<128, 64><<<dim3(2, (N + 127) / 128), 256, 0, stream>>>(h1b, wlr2t, xlr2, N, 128, 256);
    agg2<<<(N + 3) / 4, 256, 0, stream>>>(xlr2, att2, b2, offsets, csr_off, out, N);
}

// Round 8
// 343.144 us; speedup vs baseline: 1.0065x; 1.0065x over previous
//
#include <hip/hip_runtime.h>
#include <hip/hip_bf16.h>
#include <math.h>

#define NEG_SLOPE 0.2f

typedef __attribute__((ext_vector_type(8))) short short8;
typedef __attribute__((ext_vector_type(4))) float floatx4;
typedef __attribute__((ext_vector_type(2))) float floatx2;

__device__ inline ushort f2b(float f) {
    __hip_bfloat16 b = __float2bfloat16(f);
    return *(ushort*)&b;
}
// dword holding 2 bf16 (lo, hi) -> floatx2
__device__ inline floatx2 bf2x2(unsigned int d) {
    union { unsigned int i; float f; } lo, hi;
    lo.i = d << 16;
    hi.i = d & 0xffff0000u;
    floatx2 r = {lo.f, hi.f};
    return r;
}

// async global->LDS, 16 B per lane. LDS dest = wave-uniform base + lane*16.
#define GLOAD_LDS16(gp, lp)                                                    \
    __builtin_amdgcn_global_load_lds(                                          \
        (const __attribute__((address_space(1))) unsigned int*)(gp),           \
        (__attribute__((address_space(3))) unsigned int*)(lp), 16, 0, 0)

// ---------------------------------------------------------------------------
// bf16 MFMA GEMM, m97 recipe: C[M,N] = A[M,K] @ Bt[N,K]^T, all bf16 row-major.
// K is a template constant -> fully unrolled K-loop, staging pointers hoisted
// (row clamp + address math out of the loop). global_load_lds dwordx4 into
// UNPADDED [row][32] LDS. 256 threads = 4 waves.
// BN=128: waves 2x2 of 64x64 (acc[4][4]). BN=64: waves 4x1 of 32x64.
// ---------------------------------------------------------------------------
template<int BM, int BN, int KTOT>
__global__ __launch_bounds__(256) void gemm_bf16(const ushort* __restrict__ A,
                                                 const ushort* __restrict__ Bt,
                                                 ushort* __restrict__ C,
                                                 int M, int N)
{
    constexpr int WTM = (BN == 64) ? 32 : 64;    // wave tile M
    constexpr int WM  = BM / WTM;                // waves along M
    constexpr int IT  = WTM / 16;
    constexpr int JT  = 4;                       // wave tile N = 64
    __shared__ ushort As[BM * 32];
    __shared__ ushort Bs[BN * 32];
    const int tid = threadIdx.x;
    const int w = tid >> 6, lane = tid & 63;
    const int mw = (w % WM) * WTM;
    const int nw = (w / WM) * 64;
    const int m0 = blockIdx.y * BM;
    const int n0 = blockIdx.x * BN;
    const int lm = lane & 15;
    const int kg = lane >> 4;

    // staging coords: row = tid>>2, kc = tid&3 (16 B per lane)
    const int srow = tid >> 2, skc = tid & 3;

    // hoisted staging source pointers (clamp applied once)
    const ushort* aSrc[BM / 64];
#pragma unroll
    for (int it = 0; it < BM / 64; ++it) {
        int grow = m0 + it * 64 + srow;
        if (grow >= M) grow = M - 1;
        aSrc[it] = A + (size_t)grow * KTOT + skc * 8;
    }
    const ushort* bSrc[BN / 64];
#pragma unroll
    for (int it = 0; it < BN / 64; ++it)
        bSrc[it] = Bt + (size_t)(n0 + it * 64 + srow) * KTOT + skc * 8;

    floatx4 acc[IT][JT];
#pragma unroll
    for (int i = 0; i < IT; ++i)
#pragma unroll
        for (int j = 0; j < JT; ++j) acc[i][j] = (floatx4)0.f;

#pragma unroll
    for (int k0 = 0; k0 < KTOT; k0 += 32) {
#pragma unroll
        for (int it = 0; it < BM / 64; ++it)
            GLOAD_LDS16(aSrc[it] + k0, As + (it * 256 + w * 64) * 8);
#pragma unroll
        for (int it = 0; it < BN / 64; ++it)
            GLOAD_LDS16(bSrc[it] + k0, Bs + (it * 256 + w * 64) * 8);
        __syncthreads();                         // drains vmcnt before barrier
        short8 a[IT], b[JT];
#pragma unroll
        for (int i = 0; i < IT; ++i)
            a[i] = *(const short8*)&As[(mw + i * 16 + lm) * 32 + kg * 8];
#pragma unroll
        for (int j = 0; j < JT; ++j)
            b[j] = *(const short8*)&Bs[(nw + j * 16 + lm) * 32 + kg * 8];
#pragma unroll
        for (int i = 0; i < IT; ++i)
#pragma unroll
            for (int j = 0; j < JT; ++j)
                acc[i][j] = __builtin_amdgcn_mfma_f32_16x16x32_bf16(a[i], b[j], acc[i][j], 0, 0, 0);
        __syncthreads();
    }

#pragma unroll
    for (int i = 0; i < IT; ++i) {
        int rbase = m0 + mw + i * 16 + (lane >> 4) * 4;
#pragma unroll
        for (int j = 0; j < JT; ++j) {
            int col = n0 + nw + j * 16 + lm;
#pragma unroll
            for (int r = 0; r < 4; ++r) {
                int row = rbase + r;
                if (row < M) C[(size_t)row * N + col] = f2b(acc[i][j][r]);
            }
        }
    }
}

// ---------------------------------------------------------------------------
// Fused prep: x fp32->bf16 cast, 4 weight transposes+casts, degree count.
// counts must be zeroed first (stream-ordered memset).
// ---------------------------------------------------------------------------
__global__ void k_prep(const float* __restrict__ x, ushort* __restrict__ xb, int XB,
                       const float* __restrict__ Wl1, const float* __restrict__ Wr1,
                       const float* __restrict__ Wl2, const float* __restrict__ Wr2,
                       ushort* __restrict__ wlr1t, ushort* __restrict__ wlr2t,
                       const int* __restrict__ dst, int E, int* __restrict__ counts)
{
    const int b = blockIdx.x;
    const int t = threadIdx.x;
    if (b < XB) {                                 // x cast: 8 floats/thread
        int i = b * 2048 + t * 8;
        float4 f0 = *(const float4*)&x[i];
        float4 f1 = *(const float4*)&x[i + 4];
        short8 o;
        o[0] = (short)f2b(f0.x); o[1] = (short)f2b(f0.y);
        o[2] = (short)f2b(f0.z); o[3] = (short)f2b(f0.w);
        o[4] = (short)f2b(f1.x); o[5] = (short)f2b(f1.y);
        o[6] = (short)f2b(f1.z); o[7] = (short)f2b(f1.w);
        *(short8*)&xb[i] = o;
    } else if (b < XB + 640) {                    // 163840 weight elements
        int i = (b - XB) * 256 + t;
        if (i < 65536) {
            int k = i >> 8, n = i & 255;
            wlr1t[n * 256 + k] = f2b(Wl1[i]);
        } else if (i < 131072) {
            int j = i - 65536;
            int k = j >> 8, n = j & 255;
            wlr1t[65536 + n * 256 + k] = f2b(Wr1[j]);
        } else if (i < 147456) {
            int j = i - 131072;
            int k = j >> 6, n = j & 63;
            wlr2t[n * 256 + k] = f2b(Wl2[j]);
        } else {
            int j = i - 147456;
            int k = j >> 6, n = j & 63;
            wlr2t[16384 + n * 256 + k] = f2b(Wr2[j]);
        }
    } else {
        int i = (b - XB - 640) * 256 + t;
        if (i < E) atomicAdd(&counts[dst[i]], 1);
    }
}

// ---------------------------------------------------------------------------
// CSR build. csr_off stores BYTE offsets into xlr1 (src*1024); agg2 uses >>2.
// csr_off[E..E+16) zero-padded (by k_fill) so agg prefetches are branchless.
// ---------------------------------------------------------------------------
__global__ void k_chunksum(const int* __restrict__ counts, int N, int* __restrict__ chunk)
{
    __shared__ int sm[256];
    const int t = threadIdx.x;
    const int base = blockIdx.x * 1024;
    int s = 0;
    for (int i = t; i < 1024; i += 256) {
        int idx = base + i;
        s += (idx < N) ? counts[idx] : 0;
    }
    sm[t] = s;
    __syncthreads();
    for (int off = 128; off; off >>= 1) {
        if (t < off) sm[t] += sm[t + off];
        __syncthreads();
    }
    if (t == 0) chunk[blockIdx.x] = sm[0];
}

// Each block redundantly scans the <=64 chunk sums in-wave (no cross-block
// sync needed), then block-scans its 1024 counts and writes offsets+cursor.
__global__ void k_scanfinish(const int* __restrict__ counts, int N,
                             const int* __restrict__ chunk, int nchunks,
                             int* __restrict__ offsets, int* __restrict__ cursor)
{
    __shared__ int sm[256];
    __shared__ int s_pref, s_total;
    const int t = threadIdx.x;
    if (t < 64) {
        int v = (t < nchunks) ? chunk[t] : 0;
        int inc = v;
#pragma unroll
        for (int off = 1; off < 64; off <<= 1) {
            int y = __shfl_up(inc, off);
            if (t >= off) inc += y;
        }
        if (t == (int)blockIdx.x) s_pref = inc - v;   // exclusive prefix
        if (t == 63) s_total = inc;
    }
    __syncthreads();
    const int base = blockIdx.x * 1024 + t * 4;
    int v[4];
    int s = 0;
#pragma unroll
    for (int i = 0; i < 4; ++i) {
        v[i] = (base + i < N) ? counts[base + i] : 0;
        s += v[i];
    }
    sm[t] = s;
    __syncthreads();
    for (int off = 1; off < 256; off <<= 1) {
        int y = (t >= off) ? sm[t - off] : 0;
        __syncthreads();
        sm[t] += y;
        __syncthreads();
    }
    int run = s_pref + sm[t] - s;
#pragma unroll
    for (int i = 0; i < 4; ++i) {
        if (base + i < N) {
            offsets[base + i] = run;
            cursor[base + i] = run;
        }
        run += v[i];
    }
    if (blockIdx.x == 0 && t == 0) offsets[N] = s_total;
}

__global__ void k_fill(const int* __restrict__ src, const int* __restrict__ dst,
                       int E, int* __restrict__ cursor, int* __restrict__ csr_off)
{
    int i = blockIdx.x * blockDim.x + threadIdx.x;
    if (i < E) {
        int d = dst[i];
        int pos = atomicAdd(&cursor[d], 1);
        csr_off[pos] = src[i] * 1024;             // byte offset into xlr1 rows
    }
    if (i < 16) csr_off[E + i] = 0;               // pad: branchless prefetch
}

// ---------------------------------------------------------------------------
// Layer-1 aggregation: one wave per node, 2 edge-slots x 32 lanes, 8 ch/lane.
// Branchless depth-2 gather prefetch (padded csr_off), packed fp32,
// single-exp online softmax, slot merge at end.
// xlr: row 1024 B (xl at +0, xr at +512 B).
// ---------------------------------------------------------------------------
__global__ __launch_bounds__(256) void agg1(const ushort* __restrict__ xlr,
                                            const float* __restrict__ att,
                                            const float* __restrict__ bias,
                                            const int* __restrict__ offsets,
                                            const int* __restrict__ csr_off,
                                            ushort* __restrict__ h1, int N)
{
    const int wave = blockIdx.x * 4 + (threadIdx.x >> 6);
    const int lane = threadIdx.x & 63;
    if (wave >= N) return;
    const int n = wave;
    const int g = lane >> 5;                        // edge slot 0/1
    const int sl = lane & 31;
    const int elem = (sl >> 2) * 32 + (sl & 3) * 8; // head*32 + quad*8
    const char* __restrict__ xbase = (const char*)xlr;
    const int ebyte = elem * 2;

    floatx2 attv2[4], xrv2[4];
    {
        uint4 xr8 = *(const uint4*)(xbase + (size_t)n * 1024 + 512 + ebyte);
        unsigned int xw[4] = {xr8.x, xr8.y, xr8.z, xr8.w};
#pragma unroll
        for (int i = 0; i < 4; ++i) {
            attv2[i] = *(const floatx2*)&att[elem + 2 * i];
            xrv2[i] = bf2x2(xw[i]);
        }
    }
    float m = -1e30f, l = 0.f;
    floatx2 acc2[4] = {(floatx2)0.f, (floatx2)0.f, (floatx2)0.f, (floatx2)0.f};

    const int beg = offsets[n], end = offsets[n + 1];
    uint4 vA, vB;
    int oC;
    {
        int k0 = beg + g;
        vA = *(const uint4*)(xbase + (unsigned)csr_off[k0] + ebyte);
        vB = *(const uint4*)(xbase + (unsigned)csr_off[k0 + 2] + ebyte);
        oC = csr_off[k0 + 4];
    }
    for (int kk = beg + g; kk < end; kk += 2) {
        uint4 cur = vA;
        vA = vB;
        vB = *(const uint4*)(xbase + (unsigned)oC + ebyte);
        oC = csr_off[kk + 6];

        unsigned int cw[4] = {cur.x, cur.y, cur.z, cur.w};
        floatx2 xl2[4];
        floatx2 u2 = (floatx2)0.f;
#pragma unroll
        for (int i = 0; i < 4; ++i) {
            xl2[i] = bf2x2(cw[i]);
            floatx2 t = xl2[i] + xrv2[i];
            t = __builtin_elementwise_max(t, t * NEG_SLOPE);   // leaky relu
            u2 += t * attv2[i];
        }
        float u = u2.x + u2.y;
        u += __shfl_xor(u, 1);                      // 4-lane channel-group reduce
        u += __shfl_xor(u, 2);
        // single-exp branchless online softmax update
        float e = __expf(-fabsf(u - m));
        bool kp = (m >= u);
        float sc = kp ? 1.f : e;
        float p  = kp ? e : 1.f;
        m = fmaxf(m, u);
#pragma unroll
        for (int i = 0; i < 4; ++i) acc2[i] = acc2[i] * sc + xl2[i] * p;
        l = fmaf(l, sc, p);
    }
    // merge the two slot states (butterfly over lane^32)
    {
        float mo = __shfl_xor(m, 32);
        float lo = __shfl_xor(l, 32);
        float nm = fmaxf(m, mo);
        float ea = __expf(m - nm);
        float eb = __expf(mo - nm);
#pragma unroll
        for (int i = 0; i < 4; ++i) {
            floatx2 ao = {__shfl_xor(acc2[i].x, 32), __shfl_xor(acc2[i].y, 32)};
            acc2[i] = acc2[i] * ea + ao * eb;
        }
        l = l * ea + lo * eb;
    }
    if (g == 0) {
        float rl = 1.f / (l + 1e-16f);
        short8 o;
#pragma unroll
        for (int i = 0; i < 4; ++i) {
            float v0 = fmaf(acc2[i].x, rl, bias[elem + 2 * i]);
            float v1 = fmaf(acc2[i].y, rl, bias[elem + 2 * i + 1]);
            o[2 * i]     = (short)f2b(fmaxf(v0, 0.f));
            o[2 * i + 1] = (short)f2b(fmaxf(v1, 0.f));
        }
        *(short8*)&h1[(size_t)n * 256 + elem] = o;
    }
}

// ---------------------------------------------------------------------------
// Layer-2 aggregation: one wave per node, 8 edge-slots x 8 lanes, 8 ch/lane
// (uint4 = 16 B gather/lane). 3-shuffle logit reduce, branchless depth-1
// prefetch, 3-stage slot merge, fused bias + log_softmax epilogue.
// xlr2: row 256 B (xl at +0, xr at +128 B); row byte offset = csr_off>>2.
// ---------------------------------------------------------------------------
__global__ __launch_bounds__(256) void agg2(const ushort* __restrict__ xlr,
                                            const float* __restrict__ att,
                                            const float* __restrict__ bias,
                                            const int* __restrict__ offsets,
                                            const int* __restrict__ csr_off,
                                            float* __restrict__ out, int N)
{
    const int wave = blockIdx.x * 4 + (threadIdx.x >> 6);
    const int lane = threadIdx.x & 63;
    if (wave >= N) return;
    const int n = wave;
    const int g = lane >> 3;          // slot 0..7
    const int cl = lane & 7;          // channel octet
    const char* __restrict__ xbase = (const char*)xlr;
    const int cbyte = cl * 16;        // 8 bf16

    floatx2 attv2[4], xrv2[4];
    {
        uint4 xr8 = *(const uint4*)(xbase + (size_t)n * 256 + 128 + cbyte);
        unsigned int xw[4] = {xr8.x, xr8.y, xr8.z, xr8.w};
#pragma unroll
        for (int i = 0; i < 4; ++i) {
            attv2[i] = *(const floatx2*)&att[cl * 8 + 2 * i];
            xrv2[i] = bf2x2(xw[i]);
        }
    }
    float m = -1e30f, l = 0.f;
    floatx2 acc2[4] = {(floatx2)0.f, (floatx2)0.f, (floatx2)0.f, (floatx2)0.f};

    const int beg = offsets[n], end = offsets[n + 1];
    uint4 vA;
    int oB;
    {
        int k0 = beg + g;
        vA = *(const uint4*)(xbase + ((unsigned)csr_off[k0] >> 2) + cbyte);
        oB = csr_off[k0 + 8];
    }
    for (int kk = beg + g; kk < end; kk += 8) {
        uint4 cur = vA;
        vA = *(const uint4*)(xbase + ((unsigned)oB >> 2) + cbyte);
        oB = csr_off[kk + 16];

        unsigned int cw[4] = {cur.x, cur.y, cur.z, cur.w};
        floatx2 xl2[4];
        floatx2 u2 = (floatx2)0.f;
#pragma unroll
        for (int i = 0; i < 4; ++i) {
            xl2[i] = bf2x2(cw[i]);
            floatx2 t = xl2[i] + xrv2[i];
            t = __builtin_elementwise_max(t, t * NEG_SLOPE);
            u2 += t * attv2[i];
        }
        float u = u2.x + u2.y;
        u += __shfl_xor(u, 1);                     // 8-lane channel reduce
        u += __shfl_xor(u, 2);
        u += __shfl_xor(u, 4);
        float e = __expf(-fabsf(u - m));
        bool kp = (m >= u);
        float sc = kp ? 1.f : e;
        float p  = kp ? e : 1.f;
        m = fmaxf(m, u);
#pragma unroll
        for (int i = 0; i < 4; ++i) acc2[i] = acc2[i] * sc + xl2[i] * p;
        l = fmaf(l, sc, p);
    }
    // merge the 8 slot states (butterfly over lane^{8,16,32})
#pragma unroll
    for (int off = 8; off <= 32; off <<= 1) {
        float mo = __shfl_xor(m, off);
        float lo = __shfl_xor(l, off);
        float nm = fmaxf(m, mo);
        float sa = __expf(m - nm);
        float sb = __expf(mo - nm);
#pragma unroll
        for (int i = 0; i < 4; ++i) {
            floatx2 ao = {__shfl_xor(acc2[i].x, off), __shfl_xor(acc2[i].y, off)};
            acc2[i] = acc2[i] * sa + ao * sb;
        }
        l = l * sa + lo * sb;
        m = nm;
    }
    float rl = 1.f / (l + 1e-16f);
    float h[8];
#pragma unroll
    for (int i = 0; i < 4; ++i) {
        h[2 * i]     = fmaf(acc2[i].x, rl, bias[cl * 8 + 2 * i]);
        h[2 * i + 1] = fmaf(acc2[i].y, rl, bias[cl * 8 + 2 * i + 1]);
    }

    // log_softmax over 64 channels (8/lane x 8 lanes)
    float mx = h[0];
#pragma unroll
    for (int i = 1; i < 8; ++i) mx = fmaxf(mx, h[i]);
    mx = fmaxf(mx, __shfl_xor(mx, 1));
    mx = fmaxf(mx, __shfl_xor(mx, 2));
    mx = fmaxf(mx, __shfl_xor(mx, 4));
    float ssum = 0.f;
#pragma unroll
    for (int i = 0; i < 8; ++i) ssum += __expf(h[i] - mx);
    ssum += __shfl_xor(ssum, 1);
    ssum += __shfl_xor(ssum, 2);
    ssum += __shfl_xor(ssum, 4);
    float lg = mx + __logf(ssum);
    if (g == 0) {
        float4 o0 = make_float4(h[0], h[1], h[2], h[3]);
        float4 o1 = make_float4(h[4], h[5], h[6], h[7]);
        *(float4*)&out[(size_t)n * 64 + cl * 8] = o0;
        *(float4*)&out[(size_t)n * 64 + cl * 8 + 4] = o1;
        float4 s0 = make_float4(h[0] - lg, h[1] - lg, h[2] - lg, h[3] - lg);
        float4 s1 = make_float4(h[4] - lg, h[5] - lg, h[6] - lg, h[7] - lg);
        *(float4*)&out[(size_t)(N + n) * 64 + cl * 8] = s0;
        *(float4*)&out[(size_t)(N + n) * 64 + cl * 8 + 4] = s1;
    }
}

// ---------------------------------------------------------------------------
extern "C" void kernel_launch(void* const* d_in, const int* in_sizes, int n_in,
                              void* d_out, int out_size, void* d_ws, size_t ws_size,
                              hipStream_t stream)
{
    const float* x    = (const float*)d_in[0];
    const int*   ei   = (const int*)d_in[1];
    const float* Wl1  = (const float*)d_in[2];
    const float* Wr1  = (const float*)d_in[3];
    const float* att1 = (const float*)d_in[4];
    const float* b1   = (const float*)d_in[5];
    const float* Wl2  = (const float*)d_in[6];
    const float* Wr2  = (const float*)d_in[7];
    const float* att2 = (const float*)d_in[8];
    const float* b2   = (const float*)d_in[9];
    float* out = (float*)d_out;

    const int F = 256;
    const int E = in_sizes[1] / 2;
    const int N = in_sizes[0] / F;

    const int* e_src = ei;
    const int* e_dst = ei + E;

    // ---- workspace layout ----
    ushort* xb    = (ushort*)d_ws;                   // [N][256] bf16 x
    ushort* wlr1t = xb + (size_t)N * 256;            // [512][256]  (Wl1|Wr1)^T
    ushort* wlr2t = wlr1t + 512 * 256;               // [128][256]  (Wl2|Wr2)^T
    ushort* xlr1  = wlr2t + 128 * 256;               // [N][512]  xl|xr
    ushort* h1b   = xlr1 + (size_t)N * 512;          // [N][256]
    ushort* xlr2  = h1b + (size_t)N * 256;           // [N][128]  xl|xr
    int* offsets  = (int*)(xlr2 + (size_t)N * 128);  // N+1
    int* cursor   = offsets + (N + 1);               // N+1
    int* counts   = cursor + (N + 1);                // N
    int* chunkoff = counts + N;                      // <=64+1
    int* csr_off  = chunkoff + 66;                   // E+16 (byte offsets, padded)

    const int nchunks = (N + 1023) / 1024;
    const int XB = (N * 256) / 2048;                 // x-cast blocks (8 elem/thread)

    // ---- fused prep (x cast + weights cast/transpose + degree count) ----
    hipMemsetAsync(counts, 0, (size_t)N * sizeof(int), stream);
    k_prep<<<XB + 640 + (E + 255) / 256, 256, 0, stream>>>(
        x, xb, XB, Wl1, Wr1, Wl2, Wr2, wlr1t, wlr2t, e_dst, E, counts);

    // ---- layer-1 GEMM ----
    gemm_bf16<128, 128, 256><<<dim3(4, (N + 127) / 128), 256, 0, stream>>>(xb, wlr1t, xlr1, N, 512);

    // ---- CSR scan + fill (fused scan: 2 dispatches) ----
    k_chunksum<<<nchunks, 256, 0, stream>>>(counts, N, chunkoff);
    k_scanfinish<<<nchunks, 256, 0, stream>>>(counts, N, chunkoff, nchunks, offsets, cursor);
    k_fill<<<(E + 255) / 256, 256, 0, stream>>>(e_src, e_dst, E, cursor, csr_off);

    // ---- layer 1 aggregate ----
    agg1<<<(N + 3) / 4, 256, 0, stream>>>(xlr1, att1, b1, offsets, csr_off, h1b, N);

    // ---- layer 2 ----
    gemm_bf16<128, 64, 256><<<dim3(2, (N + 127) / 128), 256, 0, stream>>>(h1b, wlr2t, xlr2, N, 128);
    agg2<<<(N + 3) / 4, 256, 0, stream>>>(xlr2, att2, b2, offsets, csr_off, out, N);
}

// Round 9
// 330.077 us; speedup vs baseline: 1.0463x; 1.0396x over previous
//
#include <hip/hip_runtime.h>
#include <hip/hip_bf16.h>
#include <math.h>

#define NEG_SLOPE 0.2f

typedef __attribute__((ext_vector_type(8))) short short8;
typedef __attribute__((ext_vector_type(4))) float floatx4;
typedef __attribute__((ext_vector_type(2))) float floatx2;

__device__ inline ushort f2b(float f) {
    __hip_bfloat16 b = __float2bfloat16(f);
    return *(ushort*)&b;
}
// dword holding 2 bf16 (lo, hi) -> floatx2
__device__ inline floatx2 bf2x2(unsigned int d) {
    union { unsigned int i; float f; } lo, hi;
    lo.i = d << 16;
    hi.i = d & 0xffff0000u;
    floatx2 r = {lo.f, hi.f};
    return r;
}

// ---------------------------------------------------------------------------
// bf16 MFMA GEMM: C[M,N] = A[M,K] @ Bt[N,K]^T, all bf16 row-major.
// r6-style staging: VGPR roundtrip into PADDED LDS (SA=40 -> 80 B row stride,
// 2-way-free ds_read_b128 banks; the r7 global_load_lds variant forced an
// unpadded [row][32] layout whose 64 B stride gave ~8-way conflicts).
// K template constant -> fully unrolled; staging pointers hoisted.
// 256 threads = 4 waves. BN=128: waves 2x2 of 64x64. BN=64: waves 4x1 of 32x64.
// ---------------------------------------------------------------------------
template<int BM, int BN, int KTOT>
__global__ __launch_bounds__(256) void gemm_bf16(const ushort* __restrict__ A,
                                                 const ushort* __restrict__ Bt,
                                                 ushort* __restrict__ C,
                                                 int M, int N)
{
    constexpr int SA = 40;                       // LDS row stride (pad 8 bf16)
    constexpr int WTM = (BN == 64) ? 32 : 64;    // wave tile M
    constexpr int WM  = BM / WTM;                // waves along M
    constexpr int IT  = WTM / 16;
    constexpr int JT  = 4;                       // wave tile N = 64
    __shared__ ushort As[BM * SA];
    __shared__ ushort Bs[BN * SA];
    const int tid = threadIdx.x;
    const int w = tid >> 6, lane = tid & 63;
    const int mw = (w % WM) * WTM;
    const int nw = (w / WM) * 64;
    const int m0 = blockIdx.y * BM;
    const int n0 = blockIdx.x * BN;
    const int lm = lane & 15;
    const int kg = lane >> 4;

    // staging coords: row = tid>>2, kc = tid&3 (16 B per lane)
    const int srow = tid >> 2, skc = tid & 3;

    // hoisted staging source pointers (row clamp applied once)
    const ushort* aSrc[BM / 64];
#pragma unroll
    for (int it = 0; it < BM / 64; ++it) {
        int grow = m0 + it * 64 + srow;
        if (grow >= M) grow = M - 1;
        aSrc[it] = A + (size_t)grow * KTOT + skc * 8;
    }
    const ushort* bSrc[BN / 64];
#pragma unroll
    for (int it = 0; it < BN / 64; ++it)
        bSrc[it] = Bt + (size_t)(n0 + it * 64 + srow) * KTOT + skc * 8;

    floatx4 acc[IT][JT];
#pragma unroll
    for (int i = 0; i < IT; ++i)
#pragma unroll
        for (int j = 0; j < JT; ++j) acc[i][j] = (floatx4)0.f;

#pragma unroll
    for (int k0 = 0; k0 < KTOT; k0 += 32) {
#pragma unroll
        for (int it = 0; it < BM / 64; ++it) {
            short8 v = *(const short8*)(aSrc[it] + k0);
            *(short8*)&As[(it * 64 + srow) * SA + skc * 8] = v;
        }
#pragma unroll
        for (int it = 0; it < BN / 64; ++it) {
            short8 v = *(const short8*)(bSrc[it] + k0);
            *(short8*)&Bs[(it * 64 + srow) * SA + skc * 8] = v;
        }
        __syncthreads();
        short8 a[IT], b[JT];
#pragma unroll
        for (int i = 0; i < IT; ++i)
            a[i] = *(const short8*)&As[(mw + i * 16 + lm) * SA + kg * 8];
#pragma unroll
        for (int j = 0; j < JT; ++j)
            b[j] = *(const short8*)&Bs[(nw + j * 16 + lm) * SA + kg * 8];
#pragma unroll
        for (int i = 0; i < IT; ++i)
#pragma unroll
            for (int j = 0; j < JT; ++j)
                acc[i][j] = __builtin_amdgcn_mfma_f32_16x16x32_bf16(a[i], b[j], acc[i][j], 0, 0, 0);
        __syncthreads();
    }

#pragma unroll
    for (int i = 0; i < IT; ++i) {
        int rbase = m0 + mw + i * 16 + (lane >> 4) * 4;
#pragma unroll
        for (int j = 0; j < JT; ++j) {
            int col = n0 + nw + j * 16 + lm;
#pragma unroll
            for (int r = 0; r < 4; ++r) {
                int row = rbase + r;
                if (row < M) C[(size_t)row * N + col] = f2b(acc[i][j][r]);
            }
        }
    }
}

// ---------------------------------------------------------------------------
// Fused prep: x fp32->bf16 cast, 4 weight transposes+casts, degree count.
// counts16 is LINE-STRIDED (one counter per 64 B line, index d*16) to kill
// per-line atomic serialization; must be zeroed first (3.2 MB memset).
// ---------------------------------------------------------------------------
__global__ void k_prep(const float* __restrict__ x, ushort* __restrict__ xb, int XB,
                       const float* __restrict__ Wl1, const float* __restrict__ Wr1,
                       const float* __restrict__ Wl2, const float* __restrict__ Wr2,
                       ushort* __restrict__ wlr1t, ushort* __restrict__ wlr2t,
                       const int* __restrict__ dst, int E, int* __restrict__ counts16)
{
    const int b = blockIdx.x;
    const int t = threadIdx.x;
    if (b < XB) {                                 // x cast: 8 floats/thread
        int i = b * 2048 + t * 8;
        float4 f0 = *(const float4*)&x[i];
        float4 f1 = *(const float4*)&x[i + 4];
        short8 o;
        o[0] = (short)f2b(f0.x); o[1] = (short)f2b(f0.y);
        o[2] = (short)f2b(f0.z); o[3] = (short)f2b(f0.w);
        o[4] = (short)f2b(f1.x); o[5] = (short)f2b(f1.y);
        o[6] = (short)f2b(f1.z); o[7] = (short)f2b(f1.w);
        *(short8*)&xb[i] = o;
    } else if (b < XB + 640) {                    // 163840 weight elements
        int i = (b - XB) * 256 + t;
        if (i < 65536) {
            int k = i >> 8, n = i & 255;
            wlr1t[n * 256 + k] = f2b(Wl1[i]);
        } else if (i < 131072) {
            int j = i - 65536;
            int k = j >> 8, n = j & 255;
            wlr1t[65536 + n * 256 + k] = f2b(Wr1[j]);
        } else if (i < 147456) {
            int j = i - 131072;
            int k = j >> 6, n = j & 63;
            wlr2t[n * 256 + k] = f2b(Wl2[j]);
        } else {
            int j = i - 147456;
            int k = j >> 6, n = j & 63;
            wlr2t[16384 + n * 256 + k] = f2b(Wr2[j]);
        }
    } else {
        int i = (b - XB - 640) * 256 + t;
        if (i < E) atomicAdd(&counts16[dst[i] * 16], 1);
    }
}

// ---------------------------------------------------------------------------
// CSR build. csr_off stores BYTE offsets into xlr1 (src*1024); agg2 uses >>2.
// csr_off[E..E+16) zero-padded (by k_fill) so agg prefetches are branchless.
// counts16/cursor16 are line-strided (see k_prep).
// ---------------------------------------------------------------------------
__global__ void k_chunksum(const int* __restrict__ counts16, int N, int* __restrict__ chunk)
{
    __shared__ int sm[256];
    const int t = threadIdx.x;
    const int base = blockIdx.x * 1024;
    int s = 0;
    for (int i = t; i < 1024; i += 256) {
        int idx = base + i;
        s += (idx < N) ? counts16[idx * 16] : 0;
    }
    sm[t] = s;
    __syncthreads();
    for (int off = 128; off; off >>= 1) {
        if (t < off) sm[t] += sm[t + off];
        __syncthreads();
    }
    if (t == 0) chunk[blockIdx.x] = sm[0];
}

// Each block wave-scans the <=64 chunk sums (redundantly; no cross-block
// sync), then block-scans its own 1024 counts and writes offsets + cursor.
__global__ void k_scanfinish(const int* __restrict__ counts16, int N,
                             const int* __restrict__ chunk, int nchunks,
                             int* __restrict__ offsets, int* __restrict__ cursor16)
{
    __shared__ int sm[256];
    __shared__ int s_pref, s_total;
    const int t = threadIdx.x;
    if (t < 64) {
        int v = (t < nchunks) ? chunk[t] : 0;
        int inc = v;
#pragma unroll
        for (int off = 1; off < 64; off <<= 1) {
            int y = __shfl_up(inc, off);
            if (t >= off) inc += y;
        }
        if (t == (int)blockIdx.x) s_pref = inc - v;   // exclusive prefix
        if (t == 63) s_total = inc;
    }
    __syncthreads();
    const int base = blockIdx.x * 1024 + t * 4;
    int v[4];
    int s = 0;
#pragma unroll
    for (int i = 0; i < 4; ++i) {
        v[i] = (base + i < N) ? counts16[(base + i) * 16] : 0;
        s += v[i];
    }
    sm[t] = s;
    __syncthreads();
    for (int off = 1; off < 256; off <<= 1) {
        int y = (t >= off) ? sm[t - off] : 0;
        __syncthreads();
        sm[t] += y;
        __syncthreads();
    }
    int run = s_pref + sm[t] - s;
#pragma unroll
    for (int i = 0; i < 4; ++i) {
        if (base + i < N) {
            offsets[base + i] = run;
            cursor16[(base + i) * 16] = run;
        }
        run += v[i];
    }
    if (blockIdx.x == 0 && t == 0) offsets[N] = s_total;
}

__global__ void k_fill(const int* __restrict__ src, const int* __restrict__ dst,
                       int E, int* __restrict__ cursor16, int* __restrict__ csr_off)
{
    int i = blockIdx.x * blockDim.x + threadIdx.x;
    if (i < E) {
        int d = dst[i];
        int pos = atomicAdd(&cursor16[d * 16], 1);
        csr_off[pos] = src[i] * 1024;             // byte offset into xlr1 rows
    }
    if (i < 16) csr_off[E + i] = 0;               // pad: branchless prefetch
}

// ---------------------------------------------------------------------------
// Layer-1 aggregation: one wave per node, 2 edge-slots x 32 lanes, 8 ch/lane.
// Branchless depth-2 gather prefetch (padded csr_off), packed fp32,
// single-exp online softmax, slot merge at end.
// xlr: row 1024 B (xl at +0, xr at +512 B).
// ---------------------------------------------------------------------------
__global__ __launch_bounds__(256) void agg1(const ushort* __restrict__ xlr,
                                            const float* __restrict__ att,
                                            const float* __restrict__ bias,
                                            const int* __restrict__ offsets,
                                            const int* __restrict__ csr_off,
                                            ushort* __restrict__ h1, int N)
{
    const int wave = blockIdx.x * 4 + (threadIdx.x >> 6);
    const int lane = threadIdx.x & 63;
    if (wave >= N) return;
    const int n = wave;
    const int g = lane >> 5;                        // edge slot 0/1
    const int sl = lane & 31;
    const int elem = (sl >> 2) * 32 + (sl & 3) * 8; // head*32 + quad*8
    const char* __restrict__ xbase = (const char*)xlr;
    const int ebyte = elem * 2;

    floatx2 attv2[4], xrv2[4];
    {
        uint4 xr8 = *(const uint4*)(xbase + (size_t)n * 1024 + 512 + ebyte);
        unsigned int xw[4] = {xr8.x, xr8.y, xr8.z, xr8.w};
#pragma unroll
        for (int i = 0; i < 4; ++i) {
            attv2[i] = *(const floatx2*)&att[elem + 2 * i];
            xrv2[i] = bf2x2(xw[i]);
        }
    }
    float m = -1e30f, l = 0.f;
    floatx2 acc2[4] = {(floatx2)0.f, (floatx2)0.f, (floatx2)0.f, (floatx2)0.f};

    const int beg = offsets[n], end = offsets[n + 1];
    uint4 vA, vB;
    int oC;
    {
        int k0 = beg + g;
        vA = *(const uint4*)(xbase + (unsigned)csr_off[k0] + ebyte);
        vB = *(const uint4*)(xbase + (unsigned)csr_off[k0 + 2] + ebyte);
        oC = csr_off[k0 + 4];
    }
    for (int kk = beg + g; kk < end; kk += 2) {
        uint4 cur = vA;
        vA = vB;
        vB = *(const uint4*)(xbase + (unsigned)oC + ebyte);
        oC = csr_off[kk + 6];

        unsigned int cw[4] = {cur.x, cur.y, cur.z, cur.w};
        floatx2 xl2[4];
        floatx2 u2 = (floatx2)0.f;
#pragma unroll
        for (int i = 0; i < 4; ++i) {
            xl2[i] = bf2x2(cw[i]);
            floatx2 t = xl2[i] + xrv2[i];
            t = __builtin_elementwise_max(t, t * NEG_SLOPE);   // leaky relu
            u2 += t * attv2[i];
        }
        float u = u2.x + u2.y;
        u += __shfl_xor(u, 1);                      // 4-lane channel-group reduce
        u += __shfl_xor(u, 2);
        // single-exp branchless online softmax update
        float e = __expf(-fabsf(u - m));
        bool kp = (m >= u);
        float sc = kp ? 1.f : e;
        float p  = kp ? e : 1.f;
        m = fmaxf(m, u);
#pragma unroll
        for (int i = 0; i < 4; ++i) acc2[i] = acc2[i] * sc + xl2[i] * p;
        l = fmaf(l, sc, p);
    }
    // merge the two slot states (butterfly over lane^32)
    {
        float mo = __shfl_xor(m, 32);
        float lo = __shfl_xor(l, 32);
        float nm = fmaxf(m, mo);
        float ea = __expf(m - nm);
        float eb = __expf(mo - nm);
#pragma unroll
        for (int i = 0; i < 4; ++i) {
            floatx2 ao = {__shfl_xor(acc2[i].x, 32), __shfl_xor(acc2[i].y, 32)};
            acc2[i] = acc2[i] * ea + ao * eb;
        }
        l = l * ea + lo * eb;
    }
    if (g == 0) {
        float rl = 1.f / (l + 1e-16f);
        short8 o;
#pragma unroll
        for (int i = 0; i < 4; ++i) {
            float v0 = fmaf(acc2[i].x, rl, bias[elem + 2 * i]);
            float v1 = fmaf(acc2[i].y, rl, bias[elem + 2 * i + 1]);
            o[2 * i]     = (short)f2b(fmaxf(v0, 0.f));
            o[2 * i + 1] = (short)f2b(fmaxf(v1, 0.f));
        }
        *(short8*)&h1[(size_t)n * 256 + elem] = o;
    }
}

// ---------------------------------------------------------------------------
// Layer-2 aggregation: TWO nodes per wave (32 lanes each), 4 edge-slots x
// 8 lanes x 8 ch/lane (uint4 gather). 3-shuffle logit reduce, branchless
// depth-1 prefetch, 2-stage slot merge (within half-wave), fused bias +
// log_softmax epilogue. xlr2: row 256 B (xl +0, xr +128 B); offset=csr>>2.
// ---------------------------------------------------------------------------
__global__ __launch_bounds__(256) void agg2(const ushort* __restrict__ xlr,
                                            const float* __restrict__ att,
                                            const float* __restrict__ bias,
                                            const int* __restrict__ offsets,
                                            const int* __restrict__ csr_off,
                                            float* __restrict__ out, int N)
{
    const int wave = blockIdx.x * 4 + (threadIdx.x >> 6);
    const int lane = threadIdx.x & 63;
    const int n = wave * 2 + (lane >> 5);           // node (2 per wave)
    if (n >= N) return;
    const int sub = lane & 31;
    const int g = sub >> 3;           // slot 0..3
    const int cl = sub & 7;           // channel octet
    const char* __restrict__ xbase = (const char*)xlr;
    const int cbyte = cl * 16;        // 8 bf16

    floatx2 attv2[4], xrv2[4];
    {
        uint4 xr8 = *(const uint4*)(xbase + (size_t)n * 256 + 128 + cbyte);
        unsigned int xw[4] = {xr8.x, xr8.y, xr8.z, xr8.w};
#pragma unroll
        for (int i = 0; i < 4; ++i) {
            attv2[i] = *(const floatx2*)&att[cl * 8 + 2 * i];
            xrv2[i] = bf2x2(xw[i]);
        }
    }
    float m = -1e30f, l = 0.f;
    floatx2 acc2[4] = {(floatx2)0.f, (floatx2)0.f, (floatx2)0.f, (floatx2)0.f};

    const int beg = offsets[n], end = offsets[n + 1];
    uint4 vA;
    int oB;
    {
        int k0 = beg + g;
        vA = *(const uint4*)(xbase + ((unsigned)csr_off[k0] >> 2) + cbyte);
        oB = csr_off[k0 + 4];
    }
    for (int kk = beg + g; kk < end; kk += 4) {
        uint4 cur = vA;
        vA = *(const uint4*)(xbase + ((unsigned)oB >> 2) + cbyte);
        oB = csr_off[kk + 8];

        unsigned int cw[4] = {cur.x, cur.y, cur.z, cur.w};
        floatx2 xl2[4];
        floatx2 u2 = (floatx2)0.f;
#pragma unroll
        for (int i = 0; i < 4; ++i) {
            xl2[i] = bf2x2(cw[i]);
            floatx2 t = xl2[i] + xrv2[i];
            t = __builtin_elementwise_max(t, t * NEG_SLOPE);
            u2 += t * attv2[i];
        }
        float u = u2.x + u2.y;
        u += __shfl_xor(u, 1);                     // 8-lane channel reduce
        u += __shfl_xor(u, 2);
        u += __shfl_xor(u, 4);
        float e = __expf(-fabsf(u - m));
        bool kp = (m >= u);
        float sc = kp ? 1.f : e;
        float p  = kp ? e : 1.f;
        m = fmaxf(m, u);
#pragma unroll
        for (int i = 0; i < 4; ++i) acc2[i] = acc2[i] * sc + xl2[i] * p;
        l = fmaf(l, sc, p);
    }
    // merge the 4 slot states (butterfly over lane^{8,16}, within half-wave)
#pragma unroll
    for (int off = 8; off <= 16; off <<= 1) {
        float mo = __shfl_xor(m, off);
        float lo = __shfl_xor(l, off);
        float nm = fmaxf(m, mo);
        float sa = __expf(m - nm);
        float sb = __expf(mo - nm);
#pragma unroll
        for (int i = 0; i < 4; ++i) {
            floatx2 ao = {__shfl_xor(acc2[i].x, off), __shfl_xor(acc2[i].y, off)};
            acc2[i] = acc2[i] * sa + ao * sb;
        }
        l = l * sa + lo * sb;
        m = nm;
    }
    float rl = 1.f / (l + 1e-16f);
    float h[8];
#pragma unroll
    for (int i = 0; i < 4; ++i) {
        h[2 * i]     = fmaf(acc2[i].x, rl, bias[cl * 8 + 2 * i]);
        h[2 * i + 1] = fmaf(acc2[i].y, rl, bias[cl * 8 + 2 * i + 1]);
    }

    // log_softmax over 64 channels (8/lane x 8 lanes)
    float mx = h[0];
#pragma unroll
    for (int i = 1; i < 8; ++i) mx = fmaxf(mx, h[i]);
    mx = fmaxf(mx, __shfl_xor(mx, 1));
    mx = fmaxf(mx, __shfl_xor(mx, 2));
    mx = fmaxf(mx, __shfl_xor(mx, 4));
    float ssum = 0.f;
#pragma unroll
    for (int i = 0; i < 8; ++i) ssum += __expf(h[i] - mx);
    ssum += __shfl_xor(ssum, 1);
    ssum += __shfl_xor(ssum, 2);
    ssum += __shfl_xor(ssum, 4);
    float lg = mx + __logf(ssum);
    if (g == 0) {
        float4 o0 = make_float4(h[0], h[1], h[2], h[3]);
        float4 o1 = make_float4(h[4], h[5], h[6], h[7]);
        *(float4*)&out[(size_t)n * 64 + cl * 8] = o0;
        *(float4*)&out[(size_t)n * 64 + cl * 8 + 4] = o1;
        float4 s0 = make_float4(h[0] - lg, h[1] - lg, h[2] - lg, h[3] - lg);
        float4 s1 = make_float4(h[4] - lg, h[5] - lg, h[6] - lg, h[7] - lg);
        *(float4*)&out[(size_t)(N + n) * 64 + cl * 8] = s0;
        *(float4*)&out[(size_t)(N + n) * 64 + cl * 8 + 4] = s1;
    }
}

// ---------------------------------------------------------------------------
extern "C" void kernel_launch(void* const* d_in, const int* in_sizes, int n_in,
                              void* d_out, int out_size, void* d_ws, size_t ws_size,
                              hipStream_t stream)
{
    const float* x    = (const float*)d_in[0];
    const int*   ei   = (const int*)d_in[1];
    const float* Wl1  = (const float*)d_in[2];
    const float* Wr1  = (const float*)d_in[3];
    const float* att1 = (const float*)d_in[4];
    const float* b1   = (const float*)d_in[5];
    const float* Wl2  = (const float*)d_in[6];
    const float* Wr2  = (const float*)d_in[7];
    const float* att2 = (const float*)d_in[8];
    const float* b2   = (const float*)d_in[9];
    float* out = (float*)d_out;

    const int F = 256;
    const int E = in_sizes[1] / 2;
    const int N = in_sizes[0] / F;

    const int* e_src = ei;
    const int* e_dst = ei + E;

    // ---- workspace layout ----
    ushort* xb    = (ushort*)d_ws;                   // [N][256] bf16 x
    ushort* wlr1t = xb + (size_t)N * 256;            // [512][256]  (Wl1|Wr1)^T
    ushort* wlr2t = wlr1t + 512 * 256;               // [128][256]  (Wl2|Wr2)^T
    ushort* xlr1  = wlr2t + 128 * 256;               // [N][512]  xl|xr
    ushort* h1b   = xlr1 + (size_t)N * 512;          // [N][256]
    ushort* xlr2  = h1b + (size_t)N * 256;           // [N][128]  xl|xr
    int* offsets  = (int*)(xlr2 + (size_t)N * 128);  // N+1
    int* chunkoff = offsets + (N + 1);               // <=64+1
    int* csr_off  = chunkoff + 66;                   // E+16 (byte offsets, padded)
    int* counts16 = csr_off + E + 16;                // N*16 (line-strided)
    int* cursor16 = counts16 + (size_t)N * 16;       // N*16 (line-strided)

    const int nchunks = (N + 1023) / 1024;
    const int XB = (N * 256) / 2048;                 // x-cast blocks (8 elem/thread)

    // ---- fused prep (x cast + weights cast/transpose + degree count) ----
    hipMemsetAsync(counts16, 0, (size_t)N * 16 * sizeof(int), stream);
    k_prep<<<XB + 640 + (E + 255) / 256, 256, 0, stream>>>(
        x, xb, XB, Wl1, Wr1, Wl2, Wr2, wlr1t, wlr2t, e_dst, E, counts16);

    // ---- layer-1 GEMM ----
    gemm_bf16<128, 128, 256><<<dim3(4, (N + 127) / 128), 256, 0, stream>>>(xb, wlr1t, xlr1, N, 512);

    // ---- CSR scan + fill ----
    k_chunksum<<<nchunks, 256, 0, stream>>>(counts16, N, chunkoff);
    k_scanfinish<<<nchunks, 256, 0, stream>>>(counts16, N, chunkoff, nchunks, offsets, cursor16);
    k_fill<<<(E + 255) / 256, 256, 0, stream>>>(e_src, e_dst, E, cursor16, csr_off);

    // ---- layer 1 aggregate ----
    agg1<<<(N + 3) / 4, 256, 0, stream>>>(xlr1, att1, b1, offsets, csr_off, h1b, N);

    // ---- layer 2 ----
    gemm_bf16<128, 64, 256><<<dim3(2, (N + 127) / 128), 256, 0, stream>>>(h1b, wlr2t, xlr2, N, 128);
    agg2<<<(N + 7) / 8, 256, 0, stream>>>(xlr2, att2, b2, offsets, csr_off, out, N);
}